// Round 4
// baseline (72.759 us; speedup 1.0000x reference)
//
#include <hip/hip_runtime.h>
#include <hip/hip_bf16.h>

// out[b] = dot(user_factors[user_indices[b]], s)
// s[f]   = sum_c item_factors[item_indices[c], f],  F = 64
//
// 2 graph nodes: memset(s_part + done counter) -> ONE fused kernel with a
// manual device barrier (all 512 blocks co-resident: 2/CU needed, >=8 fit).
// Vectorized gathers: lane (rg=l>>4, fs=l&15) loads float4 slice fs of row rg
// -> one dwordx4 wave-instruction fetches 4 full 256B rows, coalesced.

#define FDIM 64
#define NBLOCKS 512
#define NTHREADS 256
#define WPB 4                 // waves per block
#define NCOPY 16              // spread copies of s
#define ROWS_PER_WAVE 8       // 16384 / (512*4)

__global__ void __launch_bounds__(NTHREADS, 2)
mf_fused(const int* __restrict__ user_idx, const int* __restrict__ item_idx,
         const float* __restrict__ user_factors, const float* __restrict__ item_factors,
         float* __restrict__ out, float* __restrict__ s_part,
         unsigned* __restrict__ done, int B) {
    const int lane = threadIdx.x & 63;
    const int wid  = threadIdx.x >> 6;
    const int rg   = lane >> 4;   // row-group 0..3 within the wave
    const int fs   = lane & 15;   // feature slice: floats [fs*4, fs*4+4)
    const int wave = blockIdx.x * WPB + wid;

    // ---- indices for this wave's 8 item rows + 8 user rows (k=0,1) ----
    int p[2], ii[2], ui[2];
    #pragma unroll
    for (int k = 0; k < 2; ++k) {
        p[k] = wave * ROWS_PER_WAVE + k * 4 + rg;
        const bool ok = p[k] < B;
        ii[k] = ok ? item_idx[p[k]] : -1;
        ui[k] = ok ? user_idx[p[k]] : -1;
    }

    // ---- issue ALL gathers (item + user) together: 4 dwordx4 per lane ----
    float4 urow[2];
    float4 iacc = make_float4(0.f, 0.f, 0.f, 0.f);
    #pragma unroll
    for (int k = 0; k < 2; ++k) {
        float4 iv = (ii[k] >= 0)
            ? *(const float4*)(item_factors + (size_t)ii[k] * FDIM + fs * 4)
            : make_float4(0.f, 0.f, 0.f, 0.f);
        urow[k] = (ui[k] >= 0)
            ? *(const float4*)(user_factors + (size_t)ui[k] * FDIM + fs * 4)
            : make_float4(0.f, 0.f, 0.f, 0.f);
        iacc.x += iv.x; iacc.y += iv.y; iacc.z += iv.z; iacc.w += iv.w;
    }

    // ---- sum item slices across the 4 row-groups (lane bits 4,5) ----
    #pragma unroll
    for (int m = 16; m <= 32; m <<= 1) {
        iacc.x += __shfl_xor(iacc.x, m);
        iacc.y += __shfl_xor(iacc.y, m);
        iacc.z += __shfl_xor(iacc.z, m);
        iacc.w += __shfl_xor(iacc.w, m);
    }

    // ---- block reduce (4 waves) then spread atomics into one s copy ----
    __shared__ float4 red[WPB][16];
    if (lane < 16) red[wid][fs] = iacc;
    __syncthreads();
    if (threadIdx.x < 16) {
        const float4 a = red[0][threadIdx.x], b = red[1][threadIdx.x],
                     c = red[2][threadIdx.x], d = red[3][threadIdx.x];
        float4 t;
        t.x = a.x + b.x + c.x + d.x;
        t.y = a.y + b.y + c.y + d.y;
        t.z = a.z + b.z + c.z + d.z;
        t.w = a.w + b.w + c.w + d.w;
        float* dst = s_part + (blockIdx.x & (NCOPY - 1)) * FDIM + threadIdx.x * 4;
        atomicAdd(dst + 0, t.x);
        atomicAdd(dst + 1, t.y);
        atomicAdd(dst + 2, t.z);
        atomicAdd(dst + 3, t.w);
    }
    __syncthreads();   // drains vmcnt: this block's atomics are performed

    // ---- device barrier: arrive + spin (all blocks co-resident) ----
    if (threadIdx.x == 0) {
        __threadfence();
        atomicAdd(done, 1u);
        const unsigned g = (unsigned)gridDim.x;
        while (atomicAdd(done, 0u) < g) __builtin_amdgcn_s_sleep(8);
    }
    __syncthreads();
    __threadfence();   // acquire: subsequent reads see device-coherent data

    // ---- s slice = sum of the 16 spread copies (L2-hot float4 loads) ----
    float4 s4 = make_float4(0.f, 0.f, 0.f, 0.f);
    #pragma unroll
    for (int k = 0; k < NCOPY; ++k) {
        const float4 sv = *(const float4*)(s_part + k * FDIM + fs * 4);
        s4.x += sv.x; s4.y += sv.y; s4.z += sv.z; s4.w += sv.w;
    }

    // ---- dots: lane holds u-slice; reduce across the 16-lane group ----
    #pragma unroll
    for (int k = 0; k < 2; ++k) {
        float v = urow[k].x * s4.x + urow[k].y * s4.y +
                  urow[k].z * s4.z + urow[k].w * s4.w;
        v += __shfl_xor(v, 1);
        v += __shfl_xor(v, 2);
        v += __shfl_xor(v, 4);
        v += __shfl_xor(v, 8);
        if (fs == 0 && p[k] < B) out[p[k]] = v;
    }
}

extern "C" void kernel_launch(void* const* d_in, const int* in_sizes, int n_in,
                              void* d_out, int out_size, void* d_ws, size_t ws_size,
                              hipStream_t stream) {
    const int*   user_idx     = (const int*)d_in[0];
    const int*   item_idx     = (const int*)d_in[1];
    const float* user_factors = (const float*)d_in[2];
    const float* item_factors = (const float*)d_in[3];
    float*       out          = (float*)d_out;
    float*       s_part       = (float*)d_ws;                       // NCOPY*FDIM floats
    unsigned*    done         = (unsigned*)((char*)d_ws + 4096);    // barrier counter
    const int B = in_sizes[0];

    // zero s_part (4 KB) + done counter in one node
    hipMemsetAsync(d_ws, 0, 4096 + 64, stream);

    mf_fused<<<NBLOCKS, NTHREADS, 0, stream>>>(
        user_idx, item_idx, user_factors, item_factors, out, s_part, done, B);
}

// Round 6
// 12.616 us; speedup vs baseline: 5.7673x; 5.7673x over previous
//
#include <hip/hip_runtime.h>
#include <hip/hip_bf16.h>

// out[b] = dot(user_factors[user_indices[b]], s)
// s[f]   = sum_c item_factors[item_indices[c], f],  F = 64
//
// 2 graph nodes, no memset, no atomics:
//   node 1: mf_item_sum  (64 blocks) -> s_part[64][64] plain stores
//   node 2: mf_user_dot  (512 blocks) -> block-sums s_part in LDS, then dots
// Lane decomposition everywhere: rg = lane>>4 (row group 0..3),
// fs = lane&15 (float4 feature slice) -> one dwordx4 wave-inst = 4 rows.

#define FDIM 64
#define NB1 64            // item_sum blocks == NCOPY
#define NB2 512           // user_dot blocks
#define NTHREADS 256
#define WPB 4             // waves per block
#define R1 16             // gather rounds per wave in item_sum (64 rows/wave)
#define R2 2              // gather rounds per wave in user_dot (8 rows/wave)

__global__ void __launch_bounds__(NTHREADS)
mf_item_sum(const int* __restrict__ item_idx,
            const float* __restrict__ item_factors,
            float* __restrict__ s_part, int B) {
    const int lane = threadIdx.x & 63;
    const int wid  = threadIdx.x >> 6;
    const int rg   = lane >> 4;
    const int fs   = lane & 15;
    const int waveBase = (blockIdx.x * WPB + wid) * (R1 * 4);  // 64 rows/wave

    // Preload all 16 indices (independent, 16-lane broadcast each).
    int idx[R1];
    #pragma unroll
    for (int r = 0; r < R1; ++r) {
        const int p = waveBase + r * 4 + rg;
        idx[r] = (p < B) ? item_idx[p] : -1;
    }

    // 16 independent float4 row-gathers, accumulate.
    float4 acc = make_float4(0.f, 0.f, 0.f, 0.f);
    #pragma unroll
    for (int r = 0; r < R1; ++r) {
        if (idx[r] >= 0) {
            const float4 v = *(const float4*)(item_factors + (size_t)idx[r] * FDIM + fs * 4);
            acc.x += v.x; acc.y += v.y; acc.z += v.z; acc.w += v.w;
        }
    }

    // Sum across the 4 row-groups (lane bits 4,5).
    #pragma unroll
    for (int m = 16; m <= 32; m <<= 1) {
        acc.x += __shfl_xor(acc.x, m);
        acc.y += __shfl_xor(acc.y, m);
        acc.z += __shfl_xor(acc.z, m);
        acc.w += __shfl_xor(acc.w, m);
    }

    // Block reduce across 4 waves, then plain-store this block's copy.
    __shared__ float4 red[WPB][16];
    if (lane < 16) red[wid][fs] = acc;
    __syncthreads();
    if (threadIdx.x < 16) {
        const float4 a = red[0][threadIdx.x], b = red[1][threadIdx.x],
                     c = red[2][threadIdx.x], d = red[3][threadIdx.x];
        float4 t;
        t.x = a.x + b.x + c.x + d.x;
        t.y = a.y + b.y + c.y + d.y;
        t.z = a.z + b.z + c.z + d.z;
        t.w = a.w + b.w + c.w + d.w;
        *(float4*)(s_part + blockIdx.x * FDIM + threadIdx.x * 4) = t;
    }
}

__global__ void __launch_bounds__(NTHREADS)
mf_user_dot(const int* __restrict__ user_idx,
            const float* __restrict__ user_factors,
            const float* __restrict__ s_part,
            float* __restrict__ out, int B) {
    const int lane = threadIdx.x & 63;
    const int wid  = threadIdx.x >> 6;
    const int rg   = lane >> 4;
    const int fs   = lane & 15;

    // ---- block-level: s[64] = sum of the 64 copies, once per block ----
    __shared__ float sred[4][FDIM];
    __shared__ float s_lds[FDIM];
    {
        const int f = threadIdx.x & 63;          // feature
        const int g = threadIdx.x >> 6;          // copy group 0..3
        float p = 0.f;
        #pragma unroll
        for (int c = 0; c < NB1 / 4; ++c)        // 16 copies per group
            p += s_part[(g * (NB1 / 4) + c) * FDIM + f];
        sred[g][f] = p;
    }
    __syncthreads();
    if (threadIdx.x < FDIM)
        s_lds[threadIdx.x] = sred[0][threadIdx.x] + sred[1][threadIdx.x] +
                             sred[2][threadIdx.x] + sred[3][threadIdx.x];
    __syncthreads();

    const float4 s4 = *(const float4*)(s_lds + fs * 4);

    // ---- 8 outputs per wave: 2 rounds of 4-row float4 gathers + dot ----
    const int waveBase = (blockIdx.x * WPB + wid) * (R2 * 4);
    #pragma unroll
    for (int r = 0; r < R2; ++r) {
        const int p = waveBase + r * 4 + rg;
        if (p < B) {
            const int u = user_idx[p];
            const float4 uv = *(const float4*)(user_factors + (size_t)u * FDIM + fs * 4);
            float v = uv.x * s4.x + uv.y * s4.y + uv.z * s4.z + uv.w * s4.w;
            v += __shfl_xor(v, 1);
            v += __shfl_xor(v, 2);
            v += __shfl_xor(v, 4);
            v += __shfl_xor(v, 8);
            if (fs == 0) out[p] = v;
        }
    }
}

extern "C" void kernel_launch(void* const* d_in, const int* in_sizes, int n_in,
                              void* d_out, int out_size, void* d_ws, size_t ws_size,
                              hipStream_t stream) {
    const int*   user_idx     = (const int*)d_in[0];
    const int*   item_idx     = (const int*)d_in[1];
    const float* user_factors = (const float*)d_in[2];
    const float* item_factors = (const float*)d_in[3];
    float*       out          = (float*)d_out;
    float*       s_part       = (float*)d_ws;   // NB1 * FDIM floats = 16 KB
    const int B = in_sizes[0];

    mf_item_sum<<<NB1, NTHREADS, 0, stream>>>(item_idx, item_factors, s_part, B);
    mf_user_dot<<<NB2, NTHREADS, 0, stream>>>(user_idx, user_factors, s_part, out, B);
}